// Round 7
// baseline (31.106 us; speedup 1.0000x reference)
//
#include <hip/hip_runtime.h>

// S=8192, H=2048
// v = W^T h;  energies[s] = enc[s,:].v  (+b.h softmax-invariant, dropped)
// out = softmax(energies)
// Fused producer/consumer: blocks 0..255 produce v (8 cols each), all 1024
// blocks consume (8 enc rows each). Sync = 256 per-producer flags, no RMW.
// ws floats: v[2048] | e[8192] | pairs[1024]x2 | flags[256] int

#define Hdim 2048
#define Sdim 8192
#define MAGIC 0x7E57C0DE

__global__ __launch_bounds__(256, 4) void k_fused(
    const float* __restrict__ W, const float* __restrict__ hid,
    const float* __restrict__ enc, float* __restrict__ v,
    float* __restrict__ e, float2* __restrict__ pairs, int* __restrict__ flags) {
    __shared__ float v_lds[Hdim];  // 8 KB; producers reuse first 4 KB as reduce buf
    __shared__ float se[8];
    int t = threadIdx.x, b = blockIdx.x;
    int lane = t & 63, wv = t >> 6;

    if (b < 256) {
        // ---- produce v[c0..c0+7]; XCD-contiguous col ownership (validated R5/R6) ----
        int c0 = ((b & 7) << 8) + ((b >> 3) << 3);
        int cp = (t & 1) * 4;
        int rl = t >> 1;  // 0..127
        float4 acc = {0.f, 0.f, 0.f, 0.f};
#pragma unroll
        for (int i = 0; i < 16; ++i) {
            int k = rl + (i << 7);
            float hk = hid[k];
            float4 w = *reinterpret_cast<const float4*>(W + (size_t)k * Hdim + c0 + cp);
            acc.x += w.x * hk; acc.y += w.y * hk; acc.z += w.z * hk; acc.w += w.w * hk;
        }
        float4* red = reinterpret_cast<float4*>(v_lds);
        red[t] = acc;
        __syncthreads();
        for (int s2 = 64; s2 > 0; s2 >>= 1) {
            if (rl < s2) {
                float4 o = red[t + 2 * s2]; float4 m = red[t];
                m.x += o.x; m.y += o.y; m.z += o.z; m.w += o.w;
                red[t] = m;
            }
            __syncthreads();
        }
        if (t < 2) {
            float4 r = red[t];  // t=0: cols c0..3, t=1: cols c0+4..7
            __hip_atomic_store(&v[c0 + cp + 0], r.x, __ATOMIC_RELAXED, __HIP_MEMORY_SCOPE_AGENT);
            __hip_atomic_store(&v[c0 + cp + 1], r.y, __ATOMIC_RELAXED, __HIP_MEMORY_SCOPE_AGENT);
            __hip_atomic_store(&v[c0 + cp + 2], r.z, __ATOMIC_RELAXED, __HIP_MEMORY_SCOPE_AGENT);
            __hip_atomic_store(&v[c0 + cp + 3], r.w, __ATOMIC_RELAXED, __HIP_MEMORY_SCOPE_AGENT);
        }
        asm volatile("s_waitcnt vmcnt(0)" ::: "memory");  // v durable at L3 before flag
        if (t == 0)
            __hip_atomic_store(&flags[b], MAGIC, __ATOMIC_RELAXED, __HIP_MEMORY_SCOPE_AGENT);
        __syncthreads();  // LDS reuse barrier
    }

    // ---- prefetch this wave's first enc row into registers (overlaps poll) ----
    size_t s0 = (size_t)b * 8 + wv * 2;
    const float* r0 = enc + s0 * Hdim;
    float4 pf[8];
#pragma unroll
    for (int i = 0; i < 8; ++i)
        pf[i] = *reinterpret_cast<const float4*>(r0 + i * 256 + lane * 4);

    // ---- wait: each thread spins on its own producer flag (read-only, no RMW) ----
    {
        int f;
        do {
            f = __hip_atomic_load(&flags[t], __ATOMIC_RELAXED, __HIP_MEMORY_SCOPE_AGENT);
            if (f != MAGIC) __builtin_amdgcn_s_sleep(8);
        } while (f != MAGIC);
    }
    __syncthreads();
    asm volatile("" ::: "memory");

    // ---- stage v into LDS via agent (L2-bypassing) loads ----
#pragma unroll
    for (int j = 0; j < 8; ++j) {
        int idx = j * 256 + t;
        v_lds[idx] = __hip_atomic_load(&v[idx], __ATOMIC_RELAXED, __HIP_MEMORY_SCOPE_AGENT);
    }
    __syncthreads();

    // ---- row 0 (prefetched) ----
    float acc0 = 0.f;
#pragma unroll
    for (int i = 0; i < 8; ++i) {
        float4 a = pf[i];
        float4 w = *reinterpret_cast<float4*>(&v_lds[i * 256 + lane * 4]);
        acc0 += a.x * w.x + a.y * w.y + a.z * w.z + a.w * w.w;
    }
#pragma unroll
    for (int off = 32; off > 0; off >>= 1) acc0 += __shfl_xor(acc0, off, 64);
    if (lane == 0) { e[s0] = acc0; se[wv * 2] = acc0; }

    // ---- row 1 (streamed) ----
    const float* r1 = r0 + Hdim;
    float acc1 = 0.f;
#pragma unroll
    for (int i = 0; i < 8; ++i) {
        float4 a = *reinterpret_cast<const float4*>(r1 + i * 256 + lane * 4);
        float4 w = *reinterpret_cast<float4*>(&v_lds[i * 256 + lane * 4]);
        acc1 += a.x * w.x + a.y * w.y + a.z * w.z + a.w * w.w;
    }
#pragma unroll
    for (int off = 32; off > 0; off >>= 1) acc1 += __shfl_xor(acc1, off, 64);
    if (lane == 0) { e[s0 + 1] = acc1; se[wv * 2 + 1] = acc1; }
    __syncthreads();

    if (t == 0) {
        float m = se[0];
#pragma unroll
        for (int j = 1; j < 8; ++j) m = fmaxf(m, se[j]);
        float l = 0.f;
#pragma unroll
        for (int j = 0; j < 8; ++j) l += __expf(se[j] - m);
        pairs[b] = make_float2(m, l);
    }
}

__global__ void k3_norm(const float* __restrict__ e, const float2* __restrict__ pairs,
                        float* __restrict__ out, int* __restrict__ flags) {
    // 32 blocks x 256 thr; each block redundantly reduces 1024 (m,l) pairs
    // (deterministic), normalizes its 256-chunk. Block 0 resets flags for next call.
    int t = threadIdx.x, lane = t & 63, wv = t >> 6;
    __shared__ float red[4];
    __shared__ float bM, bL;
    float2 p[4];
    float m = -1e30f;
#pragma unroll
    for (int j = 0; j < 4; ++j) { p[j] = pairs[j * 256 + t]; m = fmaxf(m, p[j].x); }
#pragma unroll
    for (int off = 32; off > 0; off >>= 1) m = fmaxf(m, __shfl_xor(m, off, 64));
    if (lane == 0) red[wv] = m;
    __syncthreads();
    if (t == 0) bM = fmaxf(fmaxf(red[0], red[1]), fmaxf(red[2], red[3]));
    __syncthreads();
    float M = bM;
    float l = 0.f;
#pragma unroll
    for (int j = 0; j < 4; ++j) l += p[j].y * __expf(p[j].x - M);
#pragma unroll
    for (int off = 32; off > 0; off >>= 1) l += __shfl_xor(l, off, 64);
    __syncthreads();
    if (lane == 0) red[wv] = l;
    __syncthreads();
    if (t == 0) bL = red[0] + red[1] + red[2] + red[3];
    __syncthreads();
    float invL = 1.0f / bL;
    int idx = blockIdx.x * 256 + t;
    out[idx] = __expf(e[idx] - M) * invL;
    if (blockIdx.x == 0)
        __hip_atomic_store(&flags[t], 0, __ATOMIC_RELAXED, __HIP_MEMORY_SCOPE_AGENT);
}

extern "C" void kernel_launch(void* const* d_in, const int* in_sizes, int n_in,
                              void* d_out, int out_size, void* d_ws, size_t ws_size,
                              hipStream_t stream) {
    const float* hid = (const float*)d_in[0];   // (1, H)
    const float* enc = (const float*)d_in[1];   // (S, 1, H)
    const float* W   = (const float*)d_in[2];   // (H, H)
    // d_in[3] = b : dropped (softmax shift-invariant)
    float* out = (float*)d_out;                 // S floats
    float* ws = (float*)d_ws;

    float* v = ws;                          // 2048
    float* e = v + Hdim;                    // 8192
    float2* pairs = (float2*)(e + Sdim);    // 1024 float2
    int* flags = (int*)(pairs + 1024);      // 256 int (MAGIC-gated: poison-safe)

    k_fused<<<1024, 256, 0, stream>>>(W, hid, enc, v, e, pairs, flags);
    k3_norm<<<32, 256, 0, stream>>>(e, pairs, out, flags);
}